// Round 4
// baseline (180.680 us; speedup 1.0000x reference)
//
#include <hip/hip_runtime.h>

// MultiScaleRoIAlign (round 8): fused single kernel, pipelined staging.
// Round-3 fused attempt (186 us) was latency/barrier-bound: 16 serialized
// stage->sample tiles, div/mod per staged element. This version:
//   - block = (roi, c-quarter of 64), 512 threads, 8 tiles of CT=8 channels
//   - wave w stages channel w of the tile: lane j -> window site j (coalesced,
//     division-free y = (int)((j+.5)*rcp(nx)))
//   - T14 split: global->reg loads for tile t+1 issued BEFORE sampling tile t,
//     ds_write after; double-buffered LDS (distinct arrays), 1 barrier/tile
//   - sampler thread = fixed (channel-lane, bin); contiguous out stores
//   - 53.8 KB LDS -> 3 blocks/CU; __launch_bounds__(512,6)
// Math identical to the verified round-3/round-0 kernels (fp32 end-to-end).

#define ROI_OUT 7
#define NSAMP   14
#define C_TOT   256
#define N_PER_B 256
#define BINS    49
#define CT      8              // channels per tile (= waves per block)
#define NT      8              // tiles per block -> 64 channels
#define CQ      64             // channels per block
#define WCAP    832            // max window floats per channel (bound ~820)
#define WSTRIDE 833
#define THREADS 512
#define KMAX    13             // ceil(WCAP/64)

__global__ __launch_bounds__(THREADS, 6)
void msroi_fused(const float* __restrict__ f0, const float* __restrict__ f1,
                 const float* __restrict__ f2, const float* __restrict__ f3,
                 const float* __restrict__ boxes, float* __restrict__ out)
{
    __shared__ float bufA[CT * WSTRIDE];   // 26656 B
    __shared__ float bufB[CT * WSTRIDE];   // 26656 B
    __shared__ int4  pY[NSAMP], pX[NSAMP];

    const int tid = threadIdx.x;
    const int roi = blockIdx.x;
    const int b   = roi >> 8;             // N_PER_B = 256

    // ---- box + level (block-uniform, verified) ----
    const float* bxp = boxes + (size_t)roi * 4;
    float bx1 = bxp[0], by1 = bxp[1], bx2 = bxp[2], by2 = bxp[3];
    float area = (bx2 - bx1) * (by2 - by1);
    float s    = sqrtf(area);
    float lvlf = floorf(4.0f + log2f(s * (1.0f / 224.0f)) + 1e-6f);
    lvlf = fminf(fmaxf(lvlf, 2.0f), 5.0f);
    int level = (int)lvlf - 2;

    const float* feat; int H, W; float scale;
    switch (level) {
        case 0:  feat = f0; H = 200; W = 200; scale = 0.25f;    break;
        case 1:  feat = f1; H = 100; W = 100; scale = 0.125f;   break;
        case 2:  feat = f2; H = 50;  W = 50;  scale = 0.0625f;  break;
        default: feat = f3; H = 25;  W = 25;  scale = 0.03125f; break;
    }
    const size_t HWsz = (size_t)H * (size_t)W;

    float x1 = bx1 * scale, y1 = by1 * scale;
    float roi_w = fmaxf(bx2 * scale - x1, 1.0f);
    float roi_h = fmaxf(by2 * scale - y1, 1.0f);
    float bin_w = roi_w * (1.0f / ROI_OUT);
    float bin_h = roi_h * (1.0f / ROI_OUT);

    // ---- sample-coordinate precompute (verified) ----
    if (tid < 2 * NSAMP) {
        bool isy = tid >= NSAMP;
        int  j   = isy ? tid - NSAMP : tid;
        int  pb  = j >> 1, sub = j & 1;
        float start = isy ? y1 : x1;
        float bsz   = isy ? bin_h : bin_w;
        int   lim   = isy ? H : W;
        float ss = start + (float)pb * bsz + ((float)sub + 0.5f) * bsz * 0.5f;
        float v  = (ss >= -1.0f && ss <= (float)lim) ? 1.0f : 0.0f;
        float cc = fminf(fmaxf(ss, 0.0f), (float)lim - 1.0f);
        int   i0 = (int)floorf(cc);
        int   i1 = min(i0 + 1, lim - 1);
        float l  = cc - (float)i0;
        int4 pk; pk.x = i0; pk.y = i1;
        pk.z = __float_as_int(l); pk.w = __float_as_int(v);
        if (isy) pY[j] = pk; else pX[j] = pk;
    }
    __syncthreads();

    // ---- window bounds ----
    int ylo = 1 << 30, yhi = 0, xlo = 1 << 30, xhi = 0;
    #pragma unroll
    for (int j = 0; j < NSAMP; ++j) {
        int4 py = pY[j]; int4 px = pX[j];
        ylo = min(ylo, py.x); yhi = max(yhi, py.y);
        xlo = min(xlo, px.x); xhi = max(xhi, px.y);
    }
    const int ny  = yhi - ylo + 1;
    const int nx  = xhi - xlo + 1;
    const int nyx = ny * nx;
    const bool staged = (nyx <= WCAP);

    const float* fbase = feat + (size_t)b * C_TOT * HWsz;
    float*       orow  = out + (size_t)roi * (C_TOT * BINS);
    const int    cq0   = blockIdx.y * CQ;

    // staging mapping: wave w <-> channel (tile*CT + w), lane j in window
    const int w    = tid >> 6;
    const int lane = tid & 63;
    const float rnx = 1.0f / (float)nx;

    // sampler mapping: thread -> (cl, bin), fixed for all tiles
    const bool sampler = tid < CT * BINS;          // 392 of 512
    const int  cl  = tid / BINS;
    const int  bin = tid - cl * BINS;
    const int  ph  = bin / ROI_OUT;
    const int  pw  = bin - ph * ROI_OUT;

    float rv[KMAX];

    // ---- helpers ----
    auto rload = [&](int t) {
        const float* pl = fbase + (size_t)(cq0 + t * CT + w) * HWsz;
        #pragma unroll
        for (int k = 0; k < KMAX; ++k) {
            int j = lane + 64 * k;
            if (j < nyx) {
                int y = (int)(((float)j + 0.5f) * rnx);
                int x = j - y * nx;
                rv[k] = pl[(size_t)(ylo + y) * W + (xlo + x)];
            }
        }
    };
    auto dswrite = [&](float* buf) {
        float* wb = buf + w * WSTRIDE;
        #pragma unroll
        for (int k = 0; k < KMAX; ++k) {
            int j = lane + 64 * k;
            if (j < nyx) wb[j] = rv[k];
        }
    };
    auto sample = [&](const float* buf, int t) {
        if (!sampler) return;
        const float* wb = buf + cl * WSTRIDE;
        float acc = 0.0f;
        #pragma unroll
        for (int sy = 0; sy < 2; ++sy) {
            int4 py  = pY[2 * ph + sy];
            float ly = __int_as_float(py.z);
            float vy = __int_as_float(py.w);
            float hy = 1.0f - ly;
            int r0 = (py.x - ylo) * nx - xlo;
            int r1 = (py.y - ylo) * nx - xlo;
            #pragma unroll
            for (int sx = 0; sx < 2; ++sx) {
                int4 px  = pX[2 * pw + sx];
                float lx = __int_as_float(px.z);
                float vv = vy * __int_as_float(px.w);
                float hx = 1.0f - lx;
                float v00 = wb[r0 + px.x], v01 = wb[r0 + px.y];
                float v10 = wb[r1 + px.x], v11 = wb[r1 + px.y];
                acc += vv * (hy * (hx * v00 + lx * v01)
                           + ly * (hx * v10 + lx * v11));
            }
        }
        orow[(size_t)(cq0 + t * CT + cl) * BINS + bin] = acc * 0.25f;
    };

    if (staged) {
        // pipelined: rv holds tile t while tile t-1 is sampled from LDS.
        rload(0);
        for (int t = 0; t < NT; t += 2) {
            dswrite(bufA);                       // tile t -> A
            __syncthreads();                     // A ready; old B readers done
            if (t + 1 < NT) rload(t + 1);        // loads in flight during sample
            sample(bufA, t);
            if (t + 1 < NT) {
                dswrite(bufB);                   // tile t+1 -> B
                __syncthreads();
                if (t + 2 < NT) rload(t + 2);
                sample(bufB, t + 1);
            }
        }
    } else {
        // safety fallback: direct global sampling (verified round-3 path)
        if (sampler) {
            for (int t = 0; t < NT; ++t) {
                const float* pl = fbase + (size_t)(cq0 + t * CT + cl) * HWsz;
                float acc = 0.0f;
                #pragma unroll
                for (int sy = 0; sy < 2; ++sy) {
                    int4 py  = pY[2 * ph + sy];
                    float ly = __int_as_float(py.z);
                    float vy = __int_as_float(py.w);
                    float hy = 1.0f - ly;
                    const float* r0 = pl + (size_t)py.x * W;
                    const float* r1 = pl + (size_t)py.y * W;
                    #pragma unroll
                    for (int sx = 0; sx < 2; ++sx) {
                        int4 px  = pX[2 * pw + sx];
                        float lx = __int_as_float(px.z);
                        float vv = vy * __int_as_float(px.w);
                        float hx = 1.0f - lx;
                        float v00 = r0[px.x], v01 = r0[px.y];
                        float v10 = r1[px.x], v11 = r1[px.y];
                        acc += vv * (hy * (hx * v00 + lx * v01)
                                   + ly * (hx * v10 + lx * v11));
                    }
                }
                orow[(size_t)(cq0 + t * CT + cl) * BINS + bin] = acc * 0.25f;
            }
        }
    }
}

extern "C" void kernel_launch(void* const* d_in, const int* in_sizes, int n_in,
                              void* d_out, int out_size, void* d_ws, size_t ws_size,
                              hipStream_t stream)
{
    const float* f0    = (const float*)d_in[0];
    const float* f1    = (const float*)d_in[1];
    const float* f2    = (const float*)d_in[2];
    const float* f3    = (const float*)d_in[3];
    const float* boxes = (const float*)d_in[4];
    float* out = (float*)d_out;

    hipLaunchKernelGGL(msroi_fused, dim3(2 * N_PER_B, C_TOT / CQ), dim3(THREADS),
                       0, stream, f0, f1, f2, f3, boxes, out);
}

// Round 5
// 50.949 us; speedup vs baseline: 3.5463x; 3.5463x over previous
//
#include <hip/hip_runtime.h>
#include <hip/hip_fp16.h>

// MultiScaleRoIAlign (round 9): two-pass, repack staged via global_load_lds.
// Post-mortems: fused one-pass is dead (random ~112B gathers vs HBM = 1.1 TB/s
// => >=150us). Two-pass repack rounds 0/1/2 all pinned at ~3 TB/s with the
// common invariant ~1.5KB in flight per CU (latency-bound). Fix: stage via
// __builtin_amdgcn_global_load_lds width 16 (no data VGPRs, whole 16KB tile
// outstanding -> ~128KB/CU in flight). LDS dest is LINEAR (HW requirement);
// transpose-read swizzle achieved by inverse-swizzling the per-lane GLOBAL
// source (rule 21). Output = c64-plane layout [b][level][g=c/64][hw][c%64]
// (block writes 8KB contiguous; pass-2 for this layout verified in round 2).

#define ROI_OUT 7
#define NSAMP   14
#define C_TOT   256
#define N_PER_B 256
#define BINS    49
#define TOT_HW  53125          // 40000 + 10000 + 2500 + 625 per image

// hw-tile counts per level (ceil(HW/64)): 625, 157, 40, 10 -> prefix 625,782,822,832
#define NTILE_X 832

// XOR swizzle on 4-float granules within a 64-float row
#define SWZG(c) ((((c) ^ ((c) >> 3)) & 7) << 2)

typedef const __attribute__((address_space(1))) float* gas1_t;
typedef __attribute__((address_space(3))) float*       las3_t;

// ---------------- pass 1: transpose to c64-plane fp16 ----------------
__global__ __launch_bounds__(256)
void repack_kernel(const float* __restrict__ f0, const float* __restrict__ f1,
                   const float* __restrict__ f2, const float* __restrict__ f3,
                   __half* __restrict__ ws)
{
    // linear [c][p] (64x64 fp32); slot (c,p) holds feat[c][hw0 + (p ^ SWZG(c))]
    __shared__ float tile[64 * 64];

    const int tx = blockIdx.x;
    const float* feat; int HW, base, hw0;
    if (tx < 625)      { feat = f0; HW = 40000; base = 0;     hw0 = tx * 64; }
    else if (tx < 782) { feat = f1; HW = 10000; base = 40000; hw0 = (tx - 625) * 64; }
    else if (tx < 822) { feat = f2; HW = 2500;  base = 50000; hw0 = (tx - 782) * 64; }
    else               { feat = f3; HW = 625;   base = 52500; hw0 = (tx - 822) * 64; }

    const int g  = blockIdx.y;          // c-group 0..3
    const int c0 = g * 64;
    const int b  = blockIdx.z;
    const float* src = feat + ((size_t)(b * C_TOT + c0)) * (size_t)HW + hw0;

    const int t = threadIdx.x;
    const int w = t >> 6;               // wave 0..3
    const int l = t & 63;

    const bool fast = (hw0 + 64 <= HW) && ((HW & 3) == 0);

    if (fast) {
        // wave w issues 4 global_load_lds_dwordx4 (instr q = 4w+i fills c-rows 4q..4q+3)
        const int cq = l >> 4;           // 0..3 within instr
        const int hl = (l & 15) * 4;     // hw quad within row
        #pragma unroll
        for (int i = 0; i < 4; ++i) {
            int q = 4 * w + i;
            int c = 4 * q + cq;
            const float* gp = src + (size_t)c * HW + (hl ^ SWZG(c));
            __builtin_amdgcn_global_load_lds((gas1_t)(const void*)gp,
                                             (las3_t)(void*)(tile + q * 256),
                                             16, 0, 0);
        }
    } else {
        // tails + level 3 (HW=625, rows not 16B-aligned): guarded scalar stage
        const int hl = (t & 15) * 4;
        const int cr = t >> 4;           // 0..15
        #pragma unroll
        for (int i = 0; i < 4; ++i) {
            int c  = cr + 16 * i;
            int ps = hl ^ SWZG(c);       // source hw offset of LDS slot hl
            #pragma unroll
            for (int j = 0; j < 4; ++j) {
                int srchw = ps + j;      // SWZG is 4-aligned, so ps+j == (hl+j)^SWZG
                float v = (srchw < HW - hw0) ? src[(size_t)c * HW + srchw] : 0.0f;
                tile[c * 64 + hl + j] = v;
            }
        }
    }
    __syncthreads();   // compiler drains vmcnt (gll) / lgkmcnt before barrier

    // read transposed + convert + contiguous fp16 store.
    // lane l: channels c4..c4+3 (8B out), hw = 16w + 4i + (l>>4); 16 lanes cover
    // one 128B row, wave instr = 512B contiguous. LDS read = 2-way conflict (free).
    __half* plane = ws + ((size_t)b * TOT_HW + base) * C_TOT
                       + (size_t)g * (size_t)HW * 64 + (size_t)hw0 * 64;
    const int c4 = (l & 15) * 4;
    #pragma unroll
    for (int i = 0; i < 4; ++i) {
        int hw = 16 * w + 4 * i + (l >> 4);
        if (hw0 + hw < HW) {
            float v0 = tile[(c4 + 0) * 64 + (hw ^ SWZG(c4 + 0))];
            float v1 = tile[(c4 + 1) * 64 + (hw ^ SWZG(c4 + 1))];
            float v2 = tile[(c4 + 2) * 64 + (hw ^ SWZG(c4 + 2))];
            float v3 = tile[(c4 + 3) * 64 + (hw ^ SWZG(c4 + 3))];
            __half2 hh[2];
            hh[0] = __floats2half2_rn(v0, v1);
            hh[1] = __floats2half2_rn(v2, v3);
            *(float2*)(plane + (size_t)hw * 64 + c4) = *(const float2*)hh;
        }
    }
}

// ---------------- pass 2: per-roi pooled gather (c64-plane, verified r2) ----------------
__global__ __launch_bounds__(256)
void msroi_main(const __half* __restrict__ ws, const float* __restrict__ boxes,
                float* __restrict__ out)
{
    __shared__ float oacc[C_TOT * BINS];   // [c][bin], 50176 B
    __shared__ int4  pY[NSAMP], pX[NSAMP];

    const int tid = threadIdx.x;
    const int roi = blockIdx.x;
    const int b   = roi >> 8;

    const float* bxp = boxes + (size_t)roi * 4;
    float bx1 = bxp[0], by1 = bxp[1], bx2 = bxp[2], by2 = bxp[3];
    float area = (bx2 - bx1) * (by2 - by1);
    float s    = sqrtf(area);
    float lvlf = floorf(4.0f + log2f(s * (1.0f / 224.0f)) + 1e-6f);
    lvlf = fminf(fmaxf(lvlf, 2.0f), 5.0f);
    int level = (int)lvlf - 2;

    int H, W, lvbase; float scale;
    switch (level) {
        case 0:  H = 200; W = 200; lvbase = 0;     scale = 0.25f;    break;
        case 1:  H = 100; W = 100; lvbase = 40000; scale = 0.125f;   break;
        case 2:  H = 50;  W = 50;  lvbase = 50000; scale = 0.0625f;  break;
        default: H = 25;  W = 25;  lvbase = 52500; scale = 0.03125f; break;
    }

    float x1 = bx1 * scale, y1 = by1 * scale;
    float roi_w = fmaxf(bx2 * scale - x1, 1.0f);
    float roi_h = fmaxf(by2 * scale - y1, 1.0f);
    float bin_w = roi_w * (1.0f / ROI_OUT);
    float bin_h = roi_h * (1.0f / ROI_OUT);

    if (tid < 2 * NSAMP) {
        bool isy = tid >= NSAMP;
        int  j   = isy ? tid - NSAMP : tid;
        int  pb  = j >> 1, sub = j & 1;
        float start = isy ? y1 : x1;
        float bsz   = isy ? bin_h : bin_w;
        int   lim   = isy ? H : W;
        float ss = start + (float)pb * bsz + ((float)sub + 0.5f) * bsz * 0.5f;
        float v  = (ss >= -1.0f && ss <= (float)lim) ? 1.0f : 0.0f;
        float cc = fminf(fmaxf(ss, 0.0f), (float)lim - 1.0f);
        int   i0 = (int)floorf(cc);
        int   i1 = min(i0 + 1, lim - 1);
        float l  = cc - (float)i0;
        int4 pk; pk.x = i0; pk.y = i1;
        pk.z = __float_as_int(l); pk.w = __float_as_int(v);
        if (isy) pY[j] = pk; else pX[j] = pk;
    }
    __syncthreads();

    const int wave = tid >> 6;
    const int lane = tid & 63;
    const int c    = lane * 4;
    // c64-plane: group g = c/64 = lane>>4, in-plane c offset = (lane&15)*4
    const __half* gbase = ws + ((size_t)b * TOT_HW + lvbase) * C_TOT
                             + (size_t)(lane >> 4) * (size_t)(H * W) * 64
                             + (lane & 15) * 4;

    for (int bin = wave; bin < BINS; bin += 4) {
        int ph = bin / ROI_OUT;
        int pw = bin - ph * ROI_OUT;
        float a0 = 0.f, a1 = 0.f, a2 = 0.f, a3 = 0.f;

        #pragma unroll
        for (int sy = 0; sy < 2; ++sy) {
            int4 py  = pY[2 * ph + sy];
            float ly = __int_as_float(py.z);
            float vy = __int_as_float(py.w);
            float hy = 1.0f - ly;
            #pragma unroll
            for (int sx = 0; sx < 2; ++sx) {
                int4 px  = pX[2 * pw + sx];
                float lx = __int_as_float(px.z);
                float vv = vy * __int_as_float(px.w);
                float hx = 1.0f - lx;
                float w00 = vv * hy * hx, w01 = vv * hy * lx;
                float w10 = vv * ly * hx, w11 = vv * ly * lx;

                const __half2* p00 = (const __half2*)(gbase + (size_t)(py.x * W + px.x) * 64);
                const __half2* p01 = (const __half2*)(gbase + (size_t)(py.x * W + px.y) * 64);
                const __half2* p10 = (const __half2*)(gbase + (size_t)(py.y * W + px.x) * 64);
                const __half2* p11 = (const __half2*)(gbase + (size_t)(py.y * W + px.y) * 64);

                float2 g0, g1;
                g0 = __half22float2(p00[0]); g1 = __half22float2(p00[1]);
                a0 += w00 * g0.x; a1 += w00 * g0.y; a2 += w00 * g1.x; a3 += w00 * g1.y;
                g0 = __half22float2(p01[0]); g1 = __half22float2(p01[1]);
                a0 += w01 * g0.x; a1 += w01 * g0.y; a2 += w01 * g1.x; a3 += w01 * g1.y;
                g0 = __half22float2(p10[0]); g1 = __half22float2(p10[1]);
                a0 += w10 * g0.x; a1 += w10 * g0.y; a2 += w10 * g1.x; a3 += w10 * g1.y;
                g0 = __half22float2(p11[0]); g1 = __half22float2(p11[1]);
                a0 += w11 * g0.x; a1 += w11 * g0.y; a2 += w11 * g1.x; a3 += w11 * g1.y;
            }
        }
        oacc[(c + 0) * BINS + bin] = a0 * 0.25f;
        oacc[(c + 1) * BINS + bin] = a1 * 0.25f;
        oacc[(c + 2) * BINS + bin] = a2 * 0.25f;
        oacc[(c + 3) * BINS + bin] = a3 * 0.25f;
    }
    __syncthreads();

    float4*       o4 = (float4*)(out + (size_t)roi * (C_TOT * BINS));
    const float4* s4 = (const float4*)oacc;
    for (int j = tid; j < (C_TOT * BINS) / 4; j += 256) o4[j] = s4[j];
}

// ---------------- fallback: direct gather (NCHW fp32, no ws) ----------------
__global__ __launch_bounds__(256)
void msroi_direct(const float* __restrict__ f0, const float* __restrict__ f1,
                  const float* __restrict__ f2, const float* __restrict__ f3,
                  const float* __restrict__ boxes, float* __restrict__ out, int total)
{
    int e = blockIdx.x * 256 + threadIdx.x;
    if (e >= total) return;
    int bin = e % BINS;
    int c   = (e / BINS) % C_TOT;
    int roi = e / (BINS * C_TOT);
    int b   = roi / N_PER_B;

    const float* bx = boxes + (size_t)roi * 4;
    float bx1 = bx[0], by1 = bx[1], bx2 = bx[2], by2 = bx[3];
    float area = (bx2 - bx1) * (by2 - by1);
    float s    = sqrtf(area);
    float lvlf = floorf(4.0f + log2f(s * (1.0f / 224.0f)) + 1e-6f);
    lvlf = fminf(fmaxf(lvlf, 2.0f), 5.0f);
    int level = (int)lvlf - 2;

    const float* feat; int H, W; float scale;
    switch (level) {
        case 0:  feat = f0; H = 200; W = 200; scale = 0.25f;    break;
        case 1:  feat = f1; H = 100; W = 100; scale = 0.125f;   break;
        case 2:  feat = f2; H = 50;  W = 50;  scale = 0.0625f;  break;
        default: feat = f3; H = 25;  W = 25;  scale = 0.03125f; break;
    }
    float x1 = bx1 * scale, y1 = by1 * scale;
    float roi_w = fmaxf(bx2 * scale - x1, 1.0f);
    float roi_h = fmaxf(by2 * scale - y1, 1.0f);
    float bin_w = roi_w * (1.0f / ROI_OUT);
    float bin_h = roi_h * (1.0f / ROI_OUT);
    int ph = bin / ROI_OUT, pw = bin - ph * ROI_OUT;
    const float* plane = feat + ((size_t)(b * C_TOT + c)) * (size_t)(H * W);
    float Hf = (float)H, Wf = (float)W, acc = 0.0f;
    #pragma unroll
    for (int sy = 0; sy < 2; ++sy) {
        float ys = y1 + (float)ph * bin_h + ((float)sy + 0.5f) * bin_h * 0.5f;
        float vy = (ys >= -1.0f && ys <= Hf) ? 1.0f : 0.0f;
        float y  = fminf(fmaxf(ys, 0.0f), Hf - 1.0f);
        int   y0 = (int)floorf(y);
        int   y1i = min(y0 + 1, H - 1);
        float ly = y - (float)y0, hy = 1.0f - ly;
        int ro0 = y0 * W, ro1 = y1i * W;
        #pragma unroll
        for (int sx = 0; sx < 2; ++sx) {
            float xs = x1 + (float)pw * bin_w + ((float)sx + 0.5f) * bin_w * 0.5f;
            float vx = (xs >= -1.0f && xs <= Wf) ? 1.0f : 0.0f;
            float x  = fminf(fmaxf(xs, 0.0f), Wf - 1.0f);
            int   x0 = (int)floorf(x);
            int   x1i = min(x0 + 1, W - 1);
            float lx = x - (float)x0, hx = 1.0f - lx;
            float v00 = plane[ro0 + x0],  v01 = plane[ro0 + x1i];
            float v10 = plane[ro1 + x0],  v11 = plane[ro1 + x1i];
            acc += vy * vx * (hy * (hx * v00 + lx * v01) + ly * (hx * v10 + lx * v11));
        }
    }
    out[e] = acc * 0.25f;
}

extern "C" void kernel_launch(void* const* d_in, const int* in_sizes, int n_in,
                              void* d_out, int out_size, void* d_ws, size_t ws_size,
                              hipStream_t stream)
{
    const float* f0    = (const float*)d_in[0];
    const float* f1    = (const float*)d_in[1];
    const float* f2    = (const float*)d_in[2];
    const float* f3    = (const float*)d_in[3];
    const float* boxes = (const float*)d_in[4];
    float* out = (float*)d_out;

    const size_t ws_needed = (size_t)2 * TOT_HW * C_TOT * sizeof(__half); // 54.4 MB
    if (ws_size >= ws_needed) {
        __half* ws = (__half*)d_ws;
        hipLaunchKernelGGL(repack_kernel, dim3(NTILE_X, 4, 2), dim3(256), 0, stream,
                           f0, f1, f2, f3, ws);
        hipLaunchKernelGGL(msroi_main, dim3(2 * N_PER_B), dim3(256), 0, stream,
                           ws, boxes, out);
    } else {
        int total = out_size;
        hipLaunchKernelGGL(msroi_direct, dim3((total + 255) / 256), dim3(256), 0, stream,
                           f0, f1, f2, f3, boxes, out, total);
    }
}